// Round 1
// baseline (184.393 us; speedup 1.0000x reference)
//
#include <hip/hip_runtime.h>

#define S 512
#define Dm 512
#define NH 8
#define DH 64

// C[r][c] = sum_t A[r][t]*W[t][c] + bias[c]
// tile 64x64, 256 threads, micro 4x4, KC=32.
// grid 192: blk>>6 selects (W0,b0,O0)/(W1,..)/(W2,..); grid 64: only slot 0 used.
__global__ __launch_bounds__(256) void gemm3_kernel(
    const float* __restrict__ A,
    const float* __restrict__ W0, const float* __restrict__ W1, const float* __restrict__ W2,
    const float* __restrict__ b0, const float* __restrict__ b1, const float* __restrict__ b2,
    float* __restrict__ O0, float* __restrict__ O1, float* __restrict__ O2)
{
    int blk = blockIdx.x;
    int m = blk >> 6;
    int tile = blk & 63;
    const float* W = (m == 0) ? W0 : (m == 1) ? W1 : W2;
    const float* bias = (m == 0) ? b0 : (m == 1) ? b1 : b2;
    float* O = (m == 0) ? O0 : (m == 1) ? O1 : O2;
    int row0 = (tile >> 3) << 6;
    int col0 = (tile & 7) << 6;

    __shared__ float As[32][65];   // transposed: As[kk][r], +1 pad
    __shared__ float Bs[32][64];

    int u = threadIdx.x;
    int tx = u & 15, ty = u >> 4;

    float acc[4][4] = {};

    for (int k0 = 0; k0 < Dm; k0 += 32) {
        // stage A (64 rows x 32 k), transposed into As
        {
            int r = u >> 2;            // 0..63
            int cg = (u & 3) << 3;     // 0,8,16,24
            float4 a0 = *(const float4*)(A + (row0 + r) * Dm + k0 + cg);
            float4 a1 = *(const float4*)(A + (row0 + r) * Dm + k0 + cg + 4);
            As[cg + 0][r] = a0.x; As[cg + 1][r] = a0.y; As[cg + 2][r] = a0.z; As[cg + 3][r] = a0.w;
            As[cg + 4][r] = a1.x; As[cg + 5][r] = a1.y; As[cg + 6][r] = a1.z; As[cg + 7][r] = a1.w;
        }
        // stage B (32 k x 64 cols)
        {
            int kk = u >> 3;           // 0..31
            int cg = (u & 7) << 3;     // 0..56
            float4 w0 = *(const float4*)(W + (k0 + kk) * Dm + col0 + cg);
            float4 w1 = *(const float4*)(W + (k0 + kk) * Dm + col0 + cg + 4);
            *(float4*)&Bs[kk][cg] = w0;
            *(float4*)&Bs[kk][cg + 4] = w1;
        }
        __syncthreads();
        #pragma unroll
        for (int kk = 0; kk < 32; ++kk) {
            float4 av = *(const float4*)&As[kk][ty << 2];
            float4 bv = *(const float4*)&Bs[kk][tx << 2];
            float ar[4] = {av.x, av.y, av.z, av.w};
            float br[4] = {bv.x, bv.y, bv.z, bv.w};
            #pragma unroll
            for (int i = 0; i < 4; ++i)
                #pragma unroll
                for (int j = 0; j < 4; ++j)
                    acc[i][j] += ar[i] * br[j];
        }
        __syncthreads();
    }
    float4 bvv = *(const float4*)(bias + col0 + (tx << 2));
    float bb[4] = {bvv.x, bvv.y, bvv.z, bvv.w};
    #pragma unroll
    for (int i = 0; i < 4; ++i) {
        float4 o;
        o.x = acc[i][0] + bb[0];
        o.y = acc[i][1] + bb[1];
        o.z = acc[i][2] + bb[2];
        o.w = acc[i][3] + bb[3];
        *(float4*)(O + (row0 + (ty << 2) + i) * Dm + col0 + (tx << 2)) = o;
    }
}

// Attention core. 256 blocks = 8 heads * 32 i-tiles(16 rows).
// Phase A: wave w owns rows i0+4w..+3; lane = j within 64-chunk; K-row in 64 VGPRs.
//          z'[i,j] -> LDS (transpose buffer).
// Phase B: lane = d; stream V, acc += relu(v - z').
__global__ __launch_bounds__(256) void attn_kernel(
    const float* __restrict__ Q, const float* __restrict__ K, const float* __restrict__ V,
    const float* __restrict__ mask, const float* __restrict__ gamma, const float* __restrict__ alpha,
    float* __restrict__ ctx)
{
    int blk = blockIdx.x;
    int h = blk >> 5;
    int it = blk & 31;
    int i0 = it << 4;
    int c0 = h << 6;

    int u = threadIdx.x;
    int w = u >> 6;
    int lane = u & 63;

    float sc = 1.0f / (gamma[0] * 8.0f);   // sqrt(DH) = 8
    float al = alpha[0];

    __shared__ float4 zs[S][4];            // zs[j][w] = z' rows (i0+4w..+3), 32KB

    int ibase = i0 + (w << 2);

    for (int cj = 0; cj < 8; ++cj) {
        int j = (cj << 6) + lane;
        float kreg[64];
        #pragma unroll
        for (int t = 0; t < 16; ++t) {
            float4 kv = *(const float4*)(K + j * Dm + c0 + (t << 2));
            kreg[4 * t + 0] = kv.x; kreg[4 * t + 1] = kv.y;
            kreg[4 * t + 2] = kv.z; kreg[4 * t + 3] = kv.w;
        }
        float mv = mask[j];
        float madd = (1.0f - mv) * 1e6f;
        float zp[4];
        #pragma unroll
        for (int ii = 0; ii < 4; ++ii) {
            const float* qrow = Q + (ibase + ii) * Dm + c0;
            float a0 = 0.f, a1 = 0.f, a2 = 0.f, a3 = 0.f;
            #pragma unroll
            for (int t = 0; t < 16; ++t) {
                float4 qv = *(const float4*)(qrow + (t << 2));
                a0 += fabsf(kreg[4 * t + 0] - qv.x);
                a1 += fabsf(kreg[4 * t + 1] - qv.y);
                a2 += fabsf(kreg[4 * t + 2] - qv.z);
                a3 += fabsf(kreg[4 * t + 3] - qv.w);
            }
            float z = (a0 + a1 + a2 + a3) * sc;
            zp[ii] = fmaxf(z - al, 0.0f) + madd;
        }
        zs[j][w] = make_float4(zp[0], zp[1], zp[2], zp[3]);
    }
    __syncthreads();

    float acc0 = 0.f, acc1 = 0.f, acc2 = 0.f, acc3 = 0.f;
    #pragma unroll 8
    for (int j = 0; j < S; ++j) {
        float vj = V[j * Dm + c0 + lane];
        float4 z = zs[j][w];
        acc0 += fmaxf(vj - z.x, 0.0f);
        acc1 += fmaxf(vj - z.y, 0.0f);
        acc2 += fmaxf(vj - z.z, 0.0f);
        acc3 += fmaxf(vj - z.w, 0.0f);
    }
    ctx[(ibase + 0) * Dm + c0 + lane] = acc0;
    ctx[(ibase + 1) * Dm + c0 + lane] = acc1;
    ctx[(ibase + 2) * Dm + c0 + lane] = acc2;
    ctx[(ibase + 3) * Dm + c0 + lane] = acc3;
}

extern "C" void kernel_launch(void* const* d_in, const int* in_sizes, int n_in,
                              void* d_out, int out_size, void* d_ws, size_t ws_size,
                              hipStream_t stream) {
    const float* hs    = (const float*)d_in[0];
    const float* mask  = (const float*)d_in[1];
    const float* Wq    = (const float*)d_in[2];
    const float* bq    = (const float*)d_in[3];
    const float* Wk    = (const float*)d_in[4];
    const float* bk    = (const float*)d_in[5];
    const float* Wv    = (const float*)d_in[6];
    const float* bv    = (const float*)d_in[7];
    const float* Wo    = (const float*)d_in[8];
    const float* bo    = (const float*)d_in[9];
    const float* gamma = (const float*)d_in[10];
    const float* alpha = (const float*)d_in[11];
    float* out = (float*)d_out;

    float* Qb = (float*)d_ws;          // S*D floats = 1MB
    float* Kb = Qb + S * Dm;
    float* Vb = Kb + S * Dm;
    float* Cb = Vb + S * Dm;           // context, 1MB  (total 4MB ws)

    hipLaunchKernelGGL(gemm3_kernel, dim3(192), dim3(256), 0, stream,
                       hs, Wq, Wk, Wv, bq, bk, bv, Qb, Kb, Vb);
    hipLaunchKernelGGL(attn_kernel, dim3(256), dim3(256), 0, stream,
                       Qb, Kb, Vb, mask, gamma, alpha, Cb);
    hipLaunchKernelGGL(gemm3_kernel, dim3(64), dim3(256), 0, stream,
                       Cb, Wo, Wo, Wo, bo, bo, bo, out, out, out);
}

// Round 2
// 103.145 us; speedup vs baseline: 1.7877x; 1.7877x over previous
//
#include <hip/hip_runtime.h>

#define S 512
#define Dm 512

// ---------------- GEMM: C = A*W + bias, tile 64x64, micro 4x4 ----------------
__global__ __launch_bounds__(256) void gemm3_kernel(
    const float* __restrict__ A,
    const float* __restrict__ W0, const float* __restrict__ W1, const float* __restrict__ W2,
    const float* __restrict__ b0, const float* __restrict__ b1, const float* __restrict__ b2,
    float* __restrict__ O0, float* __restrict__ O1, float* __restrict__ O2)
{
    int blk = blockIdx.x;
    int m = blk >> 6;
    int tile = blk & 63;
    const float* W = (m == 0) ? W0 : (m == 1) ? W1 : W2;
    const float* bias = (m == 0) ? b0 : (m == 1) ? b1 : b2;
    float* O = (m == 0) ? O0 : (m == 1) ? O1 : O2;
    int row0 = (tile >> 3) << 6;
    int col0 = (tile & 7) << 6;

    __shared__ float As[32][65];
    __shared__ float Bs[32][64];

    int u = threadIdx.x;
    int tx = u & 15, ty = u >> 4;

    float acc[4][4] = {};

    for (int k0 = 0; k0 < Dm; k0 += 32) {
        {
            int r = u >> 2;
            int cg = (u & 3) << 3;
            float4 a0 = *(const float4*)(A + (row0 + r) * Dm + k0 + cg);
            float4 a1 = *(const float4*)(A + (row0 + r) * Dm + k0 + cg + 4);
            As[cg + 0][r] = a0.x; As[cg + 1][r] = a0.y; As[cg + 2][r] = a0.z; As[cg + 3][r] = a0.w;
            As[cg + 4][r] = a1.x; As[cg + 5][r] = a1.y; As[cg + 6][r] = a1.z; As[cg + 7][r] = a1.w;
        }
        {
            int kk = u >> 3;
            int cg = (u & 7) << 3;
            float4 w0 = *(const float4*)(W + (k0 + kk) * Dm + col0 + cg);
            float4 w1 = *(const float4*)(W + (k0 + kk) * Dm + col0 + cg + 4);
            *(float4*)&Bs[kk][cg] = w0;
            *(float4*)&Bs[kk][cg + 4] = w1;
        }
        __syncthreads();
        #pragma unroll
        for (int kk = 0; kk < 32; ++kk) {
            float4 av = *(const float4*)&As[kk][ty << 2];
            float4 bv = *(const float4*)&Bs[kk][tx << 2];
            float ar[4] = {av.x, av.y, av.z, av.w};
            float br[4] = {bv.x, bv.y, bv.z, bv.w};
            #pragma unroll
            for (int i = 0; i < 4; ++i)
                #pragma unroll
                for (int j = 0; j < 4; ++j)
                    acc[i][j] += ar[i] * br[j];
        }
        __syncthreads();
    }
    float4 bvv = *(const float4*)(bias + col0 + (tx << 2));
    float bb[4] = {bvv.x, bvv.y, bvv.z, bvv.w};
    #pragma unroll
    for (int i = 0; i < 4; ++i) {
        float4 o;
        o.x = acc[i][0] + bb[0];
        o.y = acc[i][1] + bb[1];
        o.z = acc[i][2] + bb[2];
        o.w = acc[i][3] + bb[3];
        *(float4*)(O + (row0 + (ty << 2) + i) * Dm + col0 + (tx << 2)) = o;
    }
}

// ---------------- Kernel A: z' scores + Zsum partials ----------------
// grid 1024 = 8 heads * 32 itiles(16) * 4 jchunks(128). 256 thr = 4 waves.
// wave: (w&1) -> j-half of chunk, (w>>1) -> i-half (8 rows).
// zp[h][i][j] = relu(z-alpha) + (1-mask[j])*1e6
// Zpart[(h*S+i)*8 + jq*2 + jw] = sum over this wave's 64 j of zp
__global__ __launch_bounds__(256) void zscore_kernel(
    const float* __restrict__ Q, const float* __restrict__ K,
    const float* __restrict__ mask, const float* __restrict__ gamma,
    const float* __restrict__ alpha,
    float* __restrict__ zp, float* __restrict__ Zpart)
{
    int blk = blockIdx.x;
    int h  = blk >> 7;
    int it = (blk >> 2) & 31;
    int jq = blk & 3;
    int i0 = it << 4;
    int c0 = h << 6;

    int u = threadIdx.x;
    int lane = u & 63;
    int w = u >> 6;
    int jw = w & 1, ih = w >> 1;

    __shared__ float KT[64][129];   // KT[d][jl], conflict-free b32 both ways

    {
        int d = u & 63;
        int jl0 = u >> 6;           // 0..3
        #pragma unroll
        for (int p = 0; p < 32; ++p) {
            int jl = (p << 2) + jl0;
            KT[d][jl] = K[((jq << 7) + jl) * Dm + c0 + d];
        }
    }
    __syncthreads();

    int jl = (jw << 6) + lane;
    int j  = (jq << 7) + jl;
    int ibase = i0 + (ih << 3);

    float zacc[8] = {};
    #pragma unroll
    for (int dc = 0; dc < 4; ++dc) {
        float kreg[16];
        #pragma unroll
        for (int t = 0; t < 16; ++t) kreg[t] = KT[(dc << 4) + t][jl];
        #pragma unroll
        for (int ii = 0; ii < 8; ++ii) {
            const float* qrow = Q + (ibase + ii) * Dm + c0 + (dc << 4);
            float a = 0.f;
            #pragma unroll
            for (int t4 = 0; t4 < 4; ++t4) {
                float4 qv = *(const float4*)(qrow + (t4 << 2));
                a += fabsf(kreg[(t4 << 2) + 0] - qv.x);
                a += fabsf(kreg[(t4 << 2) + 1] - qv.y);
                a += fabsf(kreg[(t4 << 2) + 2] - qv.z);
                a += fabsf(kreg[(t4 << 2) + 3] - qv.w);
            }
            zacc[ii] += a;
        }
    }

    float sc = 1.0f / (gamma[0] * 8.0f);
    float al = alpha[0];
    float madd = (1.0f - mask[j]) * 1e6f;

    float zs[8];
    #pragma unroll
    for (int ii = 0; ii < 8; ++ii) {
        float zpv = fmaxf(zacc[ii] * sc - al, 0.0f) + madd;
        zp[((h * S) + (ibase + ii)) * S + j] = zpv;
        float r = zpv;
        #pragma unroll
        for (int off = 32; off >= 1; off >>= 1) r += __shfl_xor(r, off, 64);
        zs[ii] = r;
    }
    if (lane == 0) {
        #pragma unroll
        for (int ii = 0; ii < 8; ++ii)
            Zpart[((h * S) + (ibase + ii)) * 8 + (jq << 1) + jw] = zs[ii];
    }
}

// ---------------- Kernel B: ctx[i][d] = sum_j max(v[j][d], z'[i][j]) - Zsum[i] ----------------
// grid 512 = 8 heads * 64 itiles(8). 512 thr = 8 waves; waves split j within staged chunk.
__global__ __launch_bounds__(512) void ctx_kernel(
    const float* __restrict__ V, const float* __restrict__ zp,
    const float* __restrict__ Zpart, float* __restrict__ ctx)
{
    int blk = blockIdx.x;
    int h = blk >> 6;
    int it = blk & 63;
    int i0 = it << 3;
    int c0 = h << 6;
    int u = threadIdx.x;
    int w = u >> 6, lane = u & 63;

    __shared__ float Vt[128][64];      // 32 KB, conflict-free b32
    __shared__ float part[8][8][64];   // 16 KB cross-wave reduce

    float acc[8] = {};

    for (int cch = 0; cch < 4; ++cch) {
        {
            int d = u & 63;
            int jl0 = u >> 6;          // 0..7
            #pragma unroll
            for (int p = 0; p < 16; ++p) {
                int jl = (p << 3) + jl0;
                Vt[jl][d] = V[((cch << 7) + jl) * Dm + c0 + d];
            }
        }
        __syncthreads();

        int jbase = w << 4;            // 16 j per wave
        float vv[16];
        #pragma unroll
        for (int t = 0; t < 16; ++t) vv[t] = Vt[jbase + t][lane];

        int jg = (cch << 7) + jbase;
        #pragma unroll
        for (int ii = 0; ii < 8; ++ii) {
            const float* zrow = zp + ((h * S) + (i0 + ii)) * S + jg;
            #pragma unroll
            for (int q4 = 0; q4 < 4; ++q4) {
                float4 z4 = *(const float4*)(zrow + (q4 << 2));
                float t0 = fmaxf(vv[(q4 << 2) + 0], z4.x) + fmaxf(vv[(q4 << 2) + 1], z4.y);
                float t1 = fmaxf(vv[(q4 << 2) + 2], z4.z) + fmaxf(vv[(q4 << 2) + 3], z4.w);
                acc[ii] += t0 + t1;
            }
        }
        __syncthreads();
    }

    #pragma unroll
    for (int ii = 0; ii < 8; ++ii) part[w][ii][lane] = acc[ii];
    __syncthreads();
    {
        int ii = u >> 6;
        float s = 0.f;
        #pragma unroll
        for (int ww = 0; ww < 8; ++ww) s += part[ww][ii][lane];
        float zsum = 0.f;
        const float* zpr = Zpart + ((h * S) + (i0 + ii)) * 8;
        #pragma unroll
        for (int p = 0; p < 8; ++p) zsum += zpr[p];
        ctx[(i0 + ii) * Dm + c0 + lane] = s - zsum;
    }
}

extern "C" void kernel_launch(void* const* d_in, const int* in_sizes, int n_in,
                              void* d_out, int out_size, void* d_ws, size_t ws_size,
                              hipStream_t stream) {
    const float* hs    = (const float*)d_in[0];
    const float* mask  = (const float*)d_in[1];
    const float* Wq    = (const float*)d_in[2];
    const float* bq    = (const float*)d_in[3];
    const float* Wk    = (const float*)d_in[4];
    const float* bk    = (const float*)d_in[5];
    const float* Wv    = (const float*)d_in[6];
    const float* bv    = (const float*)d_in[7];
    const float* Wo    = (const float*)d_in[8];
    const float* bo    = (const float*)d_in[9];
    const float* gamma = (const float*)d_in[10];
    const float* alpha = (const float*)d_in[11];
    float* out = (float*)d_out;

    float* Qb    = (float*)d_ws;             // S*Dm = 1 MB
    float* Kb    = Qb + S * Dm;              // 1 MB
    float* Vb    = Kb + S * Dm;              // 1 MB
    float* Cb    = Vb + S * Dm;              // 1 MB
    float* zpbuf = Cb + S * Dm;              // 8*S*S = 8 MB
    float* Zpart = zpbuf + 8 * S * S;        // 8*S*8 = 128 KB

    hipLaunchKernelGGL(gemm3_kernel, dim3(192), dim3(256), 0, stream,
                       hs, Wq, Wk, Wv, bq, bk, bv, Qb, Kb, Vb);
    hipLaunchKernelGGL(zscore_kernel, dim3(1024), dim3(256), 0, stream,
                       Qb, Kb, mask, gamma, alpha, zpbuf, Zpart);
    hipLaunchKernelGGL(ctx_kernel, dim3(512), dim3(512), 0, stream,
                       Vb, zpbuf, Zpart, Cb);
    hipLaunchKernelGGL(gemm3_kernel, dim3(64), dim3(256), 0, stream,
                       Cb, Wo, Wo, Wo, bo, bo, bo, out, out, out);
}

// Round 3
// 85.450 us; speedup vs baseline: 2.1579x; 1.2071x over previous
//
#include <hip/hip_runtime.h>

#define S 512
#define Dm 512

typedef __bf16 bf16x8 __attribute__((ext_vector_type(8)));
typedef float f32x4 __attribute__((ext_vector_type(4)));

// ---------------- convert hs fp32 -> bf16 row-major ----------------
__global__ __launch_bounds__(256) void conv_bf16(const float* __restrict__ X,
                                                 __bf16* __restrict__ Y)
{
    int i = (blockIdx.x * 256 + threadIdx.x) * 8;
    float4 x0 = *(const float4*)(X + i);
    float4 x1 = *(const float4*)(X + i + 4);
    bf16x8 y;
    y[0] = (__bf16)x0.x; y[1] = (__bf16)x0.y; y[2] = (__bf16)x0.z; y[3] = (__bf16)x0.w;
    y[4] = (__bf16)x1.x; y[5] = (__bf16)x1.y; y[6] = (__bf16)x1.z; y[7] = (__bf16)x1.w;
    *(bf16x8*)(Y + i) = y;
}

// ---------------- convert+transpose W[K][N] fp32 -> WT[N][K] bf16 ----------------
// grid 256 = 4 matrices * 64 tiles(64x64), 256 thr
__global__ __launch_bounds__(256) void convWT_kernel(
    const float* __restrict__ W0, const float* __restrict__ W1,
    const float* __restrict__ W2, const float* __restrict__ W3,
    __bf16* __restrict__ T0, __bf16* __restrict__ T1,
    __bf16* __restrict__ T2, __bf16* __restrict__ T3)
{
    int blk = blockIdx.x;
    int m = blk >> 6;
    int t = blk & 63;
    const float* W = (m == 0) ? W0 : (m == 1) ? W1 : (m == 2) ? W2 : W3;
    __bf16* T = (m == 0) ? T0 : (m == 1) ? T1 : (m == 2) ? T2 : T3;
    int k0 = (t >> 3) << 6;
    int n0 = (t & 7) << 6;

    __shared__ __bf16 Tl[64][72];   // [n][k], pad 72

    int u = threadIdx.x;
    {
        int kk = u >> 4;            // 0..15
        int n4 = (u & 15) << 2;     // 0..60
        #pragma unroll
        for (int p = 0; p < 4; ++p) {
            int k = kk + (p << 4);
            float4 wv = *(const float4*)(W + (k0 + k) * Dm + n0 + n4);
            Tl[n4 + 0][k] = (__bf16)wv.x;
            Tl[n4 + 1][k] = (__bf16)wv.y;
            Tl[n4 + 2][k] = (__bf16)wv.z;
            Tl[n4 + 3][k] = (__bf16)wv.w;
        }
    }
    __syncthreads();
    {
        int n = u >> 2;             // 0..63
        int ks = (u & 3) << 4;      // 0,16,32,48
        uint4 d0 = *(const uint4*)&Tl[n][ks];
        uint4 d1 = *(const uint4*)&Tl[n][ks + 8];
        *(uint4*)(T + (n0 + n) * Dm + k0 + ks) = d0;
        *(uint4*)(T + (n0 + n) * Dm + k0 + ks + 8) = d1;
    }
}

// ---------------- bf16 MFMA GEMM: O = A * W + bias (W given as WT[N][K]) ----------------
// tile 64x64, 256 thr = 4 waves; wave w: rows 16w..16w+15, all 64 cols (4 frags).
// fragments read directly from global (L2-resident).
__global__ __launch_bounds__(256) void mfma_gemm3(
    const __bf16* __restrict__ Abf,
    const __bf16* __restrict__ T0, const __bf16* __restrict__ T1, const __bf16* __restrict__ T2,
    const float* __restrict__ b0, const float* __restrict__ b1, const float* __restrict__ b2,
    float* __restrict__ O0, float* __restrict__ O1, float* __restrict__ O2)
{
    int blk = blockIdx.x;
    int m = blk >> 6;
    int tile = blk & 63;
    const __bf16* T = (m == 0) ? T0 : (m == 1) ? T1 : T2;
    const float* bias = (m == 0) ? b0 : (m == 1) ? b1 : b2;
    float* O = (m == 0) ? O0 : (m == 1) ? O1 : O2;
    int row0 = (tile >> 3) << 6;
    int col0 = (tile & 7) << 6;

    int u = threadIdx.x;
    int w = u >> 6, lane = u & 63;
    int r = lane & 15, kg = lane >> 4;

    const __bf16* Ap  = Abf + (row0 + (w << 4) + r) * Dm + (kg << 3);
    const __bf16* Bp0 = T + (col0 + 0  + r) * Dm + (kg << 3);
    const __bf16* Bp1 = T + (col0 + 16 + r) * Dm + (kg << 3);
    const __bf16* Bp2 = T + (col0 + 32 + r) * Dm + (kg << 3);
    const __bf16* Bp3 = T + (col0 + 48 + r) * Dm + (kg << 3);

    f32x4 acc0 = {0.f, 0.f, 0.f, 0.f};
    f32x4 acc1 = acc0, acc2 = acc0, acc3 = acc0;

    #pragma unroll 4
    for (int k0 = 0; k0 < Dm; k0 += 32) {
        bf16x8 a  = *(const bf16x8*)(Ap + k0);
        bf16x8 q0 = *(const bf16x8*)(Bp0 + k0);
        bf16x8 q1 = *(const bf16x8*)(Bp1 + k0);
        bf16x8 q2 = *(const bf16x8*)(Bp2 + k0);
        bf16x8 q3 = *(const bf16x8*)(Bp3 + k0);
        acc0 = __builtin_amdgcn_mfma_f32_16x16x32_bf16(a, q0, acc0, 0, 0, 0);
        acc1 = __builtin_amdgcn_mfma_f32_16x16x32_bf16(a, q1, acc1, 0, 0, 0);
        acc2 = __builtin_amdgcn_mfma_f32_16x16x32_bf16(a, q2, acc2, 0, 0, 0);
        acc3 = __builtin_amdgcn_mfma_f32_16x16x32_bf16(a, q3, acc3, 0, 0, 0);
    }

    // D: col = lane&15, row = kg*4 + t
    int orow = row0 + (w << 4) + (kg << 2);
    float bb0 = bias[col0 + 0  + r];
    float bb1 = bias[col0 + 16 + r];
    float bb2 = bias[col0 + 32 + r];
    float bb3 = bias[col0 + 48 + r];
    #pragma unroll
    for (int t = 0; t < 4; ++t) {
        O[(orow + t) * Dm + col0 + 0  + r] = acc0[t] + bb0;
        O[(orow + t) * Dm + col0 + 16 + r] = acc1[t] + bb1;
        O[(orow + t) * Dm + col0 + 32 + r] = acc2[t] + bb2;
        O[(orow + t) * Dm + col0 + 48 + r] = acc3[t] + bb3;
    }
}

// ---------------- Kernel A: z' scores + Zsum partials ----------------
__global__ __launch_bounds__(256) void zscore_kernel(
    const float* __restrict__ Q, const float* __restrict__ K,
    const float* __restrict__ mask, const float* __restrict__ gamma,
    const float* __restrict__ alpha,
    float* __restrict__ zp, float* __restrict__ Zpart)
{
    int blk = blockIdx.x;
    int h  = blk >> 7;
    int it = (blk >> 2) & 31;
    int jq = blk & 3;
    int i0 = it << 4;
    int c0 = h << 6;

    int u = threadIdx.x;
    int lane = u & 63;
    int w = u >> 6;
    int jw = w & 1, ih = w >> 1;

    __shared__ float KT[64][129];

    {
        int d = u & 63;
        int jl0 = u >> 6;
        #pragma unroll
        for (int p = 0; p < 32; ++p) {
            int jl = (p << 2) + jl0;
            KT[d][jl] = K[((jq << 7) + jl) * Dm + c0 + d];
        }
    }
    __syncthreads();

    int jl = (jw << 6) + lane;
    int j  = (jq << 7) + jl;
    int ibase = i0 + (ih << 3);

    float zacc[8] = {};
    #pragma unroll
    for (int dc = 0; dc < 4; ++dc) {
        float kreg[16];
        #pragma unroll
        for (int t = 0; t < 16; ++t) kreg[t] = KT[(dc << 4) + t][jl];
        #pragma unroll
        for (int ii = 0; ii < 8; ++ii) {
            const float* qrow = Q + (ibase + ii) * Dm + c0 + (dc << 4);
            float a = 0.f;
            #pragma unroll
            for (int t4 = 0; t4 < 4; ++t4) {
                float4 qv = *(const float4*)(qrow + (t4 << 2));
                a += fabsf(kreg[(t4 << 2) + 0] - qv.x);
                a += fabsf(kreg[(t4 << 2) + 1] - qv.y);
                a += fabsf(kreg[(t4 << 2) + 2] - qv.z);
                a += fabsf(kreg[(t4 << 2) + 3] - qv.w);
            }
            zacc[ii] += a;
        }
    }

    float sc = 1.0f / (gamma[0] * 8.0f);
    float al = alpha[0];
    float madd = (1.0f - mask[j]) * 1e6f;

    float zs[8];
    #pragma unroll
    for (int ii = 0; ii < 8; ++ii) {
        float zpv = fmaxf(zacc[ii] * sc - al, 0.0f) + madd;
        zp[((h * S) + (ibase + ii)) * S + j] = zpv;
        float r = zpv;
        #pragma unroll
        for (int off = 32; off >= 1; off >>= 1) r += __shfl_xor(r, off, 64);
        zs[ii] = r;
    }
    if (lane == 0) {
        #pragma unroll
        for (int ii = 0; ii < 8; ++ii)
            Zpart[((h * S) + (ibase + ii)) * 8 + (jq << 1) + jw] = zs[ii];
    }
}

// ---------------- Kernel B: ctx[i][d] = sum_j max(v,z') - Zsum, bf16 out ----------------
__global__ __launch_bounds__(512) void ctx_kernel(
    const float* __restrict__ V, const float* __restrict__ zp,
    const float* __restrict__ Zpart, __bf16* __restrict__ ctxb)
{
    int blk = blockIdx.x;
    int h = blk >> 6;
    int it = blk & 63;
    int i0 = it << 3;
    int c0 = h << 6;
    int u = threadIdx.x;
    int w = u >> 6, lane = u & 63;

    __shared__ float Vt[128][64];
    __shared__ float part[8][8][64];

    float acc[8] = {};

    for (int cch = 0; cch < 4; ++cch) {
        {
            int d = u & 63;
            int jl0 = u >> 6;
            #pragma unroll
            for (int p = 0; p < 16; ++p) {
                int jl = (p << 3) + jl0;
                Vt[jl][d] = V[((cch << 7) + jl) * Dm + c0 + d];
            }
        }
        __syncthreads();

        int jbase = w << 4;
        float vv[16];
        #pragma unroll
        for (int t = 0; t < 16; ++t) vv[t] = Vt[jbase + t][lane];

        int jg = (cch << 7) + jbase;
        #pragma unroll
        for (int ii = 0; ii < 8; ++ii) {
            const float* zrow = zp + ((h * S) + (i0 + ii)) * S + jg;
            #pragma unroll
            for (int q4 = 0; q4 < 4; ++q4) {
                float4 z4 = *(const float4*)(zrow + (q4 << 2));
                float t0 = fmaxf(vv[(q4 << 2) + 0], z4.x) + fmaxf(vv[(q4 << 2) + 1], z4.y);
                float t1 = fmaxf(vv[(q4 << 2) + 2], z4.z) + fmaxf(vv[(q4 << 2) + 3], z4.w);
                acc[ii] += t0 + t1;
            }
        }
        __syncthreads();
    }

    #pragma unroll
    for (int ii = 0; ii < 8; ++ii) part[w][ii][lane] = acc[ii];
    __syncthreads();
    {
        int ii = u >> 6;
        float s = 0.f;
        #pragma unroll
        for (int ww = 0; ww < 8; ++ww) s += part[ww][ii][lane];
        float zsum = 0.f;
        const float* zpr = Zpart + ((h * S) + (i0 + ii)) * 8;
        #pragma unroll
        for (int p = 0; p < 8; ++p) zsum += zpr[p];
        ctxb[(i0 + ii) * Dm + c0 + lane] = (__bf16)(s - zsum);
    }
}

extern "C" void kernel_launch(void* const* d_in, const int* in_sizes, int n_in,
                              void* d_out, int out_size, void* d_ws, size_t ws_size,
                              hipStream_t stream) {
    const float* hs    = (const float*)d_in[0];
    const float* mask  = (const float*)d_in[1];
    const float* Wq    = (const float*)d_in[2];
    const float* bq    = (const float*)d_in[3];
    const float* Wk    = (const float*)d_in[4];
    const float* bk    = (const float*)d_in[5];
    const float* Wv    = (const float*)d_in[6];
    const float* bv    = (const float*)d_in[7];
    const float* Wo    = (const float*)d_in[8];
    const float* bo    = (const float*)d_in[9];
    const float* gamma = (const float*)d_in[10];
    const float* alpha = (const float*)d_in[11];
    float* out = (float*)d_out;

    char* base = (char*)d_ws;
    float*  zp    = (float*)(base);                            // 8 MB
    float*  Zpart = (float*)(base + (8u << 20));               // 128 KB
    float*  Qb    = (float*)(base + (8u << 20) + (128u << 10));            // 1 MB
    float*  Kb    = (float*)(base + (9u << 20) + (128u << 10));            // 1 MB
    float*  Vb    = (float*)(base + (10u << 20) + (128u << 10));           // 1 MB
    __bf16* Abf   = (__bf16*)(base + (11u << 20) + (128u << 10));          // 0.5 MB
    __bf16* T0    = (__bf16*)(base + (11u << 20) + (640u << 10));          // 0.5 MB each
    __bf16* T1    = T0 + S * Dm;
    __bf16* T2    = T1 + S * Dm;
    __bf16* T3    = T2 + S * Dm;
    __bf16* Cbf   = T3 + S * Dm;                                           // 0.5 MB

    hipLaunchKernelGGL(conv_bf16, dim3(128), dim3(256), 0, stream, hs, Abf);
    hipLaunchKernelGGL(convWT_kernel, dim3(256), dim3(256), 0, stream,
                       Wq, Wk, Wv, Wo, T0, T1, T2, T3);
    hipLaunchKernelGGL(mfma_gemm3, dim3(192), dim3(256), 0, stream,
                       Abf, T0, T1, T2, bq, bk, bv, Qb, Kb, Vb);
    hipLaunchKernelGGL(zscore_kernel, dim3(1024), dim3(256), 0, stream,
                       Qb, Kb, mask, gamma, alpha, zp, Zpart);
    hipLaunchKernelGGL(ctx_kernel, dim3(512), dim3(512), 0, stream,
                       Vb, zp, Zpart, Cbf);
    hipLaunchKernelGGL(mfma_gemm3, dim3(64), dim3(256), 0, stream,
                       Cbf, T3, T3, T3, bo, bo, bo, out, out, out);
}